// Round 1
// baseline (152.281 us; speedup 1.0000x reference)
//
#include <hip/hip_runtime.h>

#define N_NODES 10000
#define E_EDGES 640000
#define C 128

// Workspace layout (floats):
//   deg  : [0,        N)        weighted in-degree incl. self-loop
//   dinv : [N,       2N)        deg^{-1/2}
//   t_a  : [2N,      3N)        sum_{e into c} w[e]*dinv[row[e]]
//   t_b  : [3N,      4N)        sum_{e from r} w[e]*dinv[col[e]]
//   s1   : [4N,      4N+128)    column sums of W1
//   g    : [4N+128,  4N+256)    sum_r beta[r]*h1[r,:]

__global__ void k_init(float* __restrict__ deg, float* __restrict__ t_a,
                       float* __restrict__ t_b, float* __restrict__ s1,
                       float* __restrict__ g, const float* __restrict__ W1) {
    int i = blockIdx.x * blockDim.x + threadIdx.x;
    if (i < N_NODES) {
        deg[i] = 1.0f;   // self-loop weight
        t_a[i] = 0.0f;
        t_b[i] = 0.0f;
    }
    if (blockIdx.x == 0 && threadIdx.x < C) {
        int j = threadIdx.x;
        float s = 0.0f;
        for (int k = 0; k < C; ++k) s += W1[k * C + j];   // coalesced across j
        s1[j] = s;
        g[j]  = 0.0f;
    }
}

__global__ void k_deg(const int* __restrict__ col, const float* __restrict__ w,
                      float* __restrict__ deg) {
    int e = blockIdx.x * blockDim.x + threadIdx.x;
    if (e < E_EDGES) atomicAdd(&deg[col[e]], w[e]);
}

__global__ void k_dinv(const float* __restrict__ deg, float* __restrict__ dinv) {
    int i = blockIdx.x * blockDim.x + threadIdx.x;
    if (i < N_NODES) dinv[i] = rsqrtf(deg[i]);   // deg >= 1 always
}

__global__ void k_scatter(const int* __restrict__ row, const int* __restrict__ col,
                          const float* __restrict__ w, const float* __restrict__ dinv,
                          float* __restrict__ t_a, float* __restrict__ t_b) {
    int e = blockIdx.x * blockDim.x + threadIdx.x;
    if (e < E_EDGES) {
        int r = row[e], c = col[e];
        float we = w[e];
        atomicAdd(&t_a[c], we * dinv[r]);
        atomicAdd(&t_b[r], we * dinv[c]);
    }
}

// g[j] = sum_i beta[i] * relu(alpha[i]*s1[j] + b1[j])
// alpha[i] = dinv[i]*t_a[i] + dinv[i]^2   (self-loop term = 1/deg)
// beta[i]  = dinv[i]*t_b[i] + dinv[i]^2
__global__ void k_greduce(const float* __restrict__ dinv, const float* __restrict__ t_a,
                          const float* __restrict__ t_b, const float* __restrict__ s1,
                          const float* __restrict__ b1, float* __restrict__ g) {
    int j = threadIdx.x;                       // channel, 0..127
    float s1j = s1[j], b1j = b1[j];
    int per = (N_NODES + gridDim.x - 1) / gridDim.x;
    int i0 = blockIdx.x * per;
    int i1 = min(i0 + per, N_NODES);
    float acc = 0.0f;
    for (int i = i0; i < i1; ++i) {
        float di    = dinv[i];                 // broadcast load (uniform addr)
        float self  = di * di;
        float alpha = di * t_a[i] + self;
        float beta  = di * t_b[i] + self;
        float h     = alpha * s1j + b1j;
        acc += beta * (h > 0.0f ? h : 0.0f);   // exact relu, no sign assumption
    }
    atomicAdd(&g[j], acc);
}

// out[j'] = (1/N) * sum_j g[j]*W2[j,j'] + b2[j']
__global__ void k_final(const float* __restrict__ g, const float* __restrict__ W2,
                        const float* __restrict__ b2, float* __restrict__ out) {
    int j = threadIdx.x;
    __shared__ float gs[C];
    gs[j] = g[j];
    __syncthreads();
    float acc = 0.0f;
    for (int k = 0; k < C; ++k) acc += gs[k] * W2[k * C + j];   // coalesced
    out[j] = acc * (1.0f / (float)N_NODES) + b2[j];
}

extern "C" void kernel_launch(void* const* d_in, const int* in_sizes, int n_in,
                              void* d_out, int out_size, void* d_ws, size_t ws_size,
                              hipStream_t stream) {
    // d_in: 0 node_features(unused), 1 edge_index(int32, 2*E), 2 edge_attributes(f32, E),
    //       3 W1, 4 b1, 5 W2, 6 b2
    const int*   eidx = (const int*)d_in[1];
    const int*   row  = eidx;            // edge_index[0]
    const int*   col  = eidx + E_EDGES;  // edge_index[1]
    const float* w    = (const float*)d_in[2];
    const float* W1   = (const float*)d_in[3];
    const float* b1   = (const float*)d_in[4];
    const float* W2   = (const float*)d_in[5];
    const float* b2   = (const float*)d_in[6];
    float* out = (float*)d_out;

    float* ws   = (float*)d_ws;
    float* deg  = ws;
    float* dinv = ws + N_NODES;
    float* t_a  = ws + 2 * N_NODES;
    float* t_b  = ws + 3 * N_NODES;
    float* s1   = ws + 4 * N_NODES;
    float* g    = ws + 4 * N_NODES + C;

    const int nodeBlocks = (N_NODES + 255) / 256;
    const int edgeBlocks = (E_EDGES + 255) / 256;

    k_init   <<<nodeBlocks, 256, 0, stream>>>(deg, t_a, t_b, s1, g, W1);
    k_deg    <<<edgeBlocks, 256, 0, stream>>>(col, w, deg);
    k_dinv   <<<nodeBlocks, 256, 0, stream>>>(deg, dinv);
    k_scatter<<<edgeBlocks, 256, 0, stream>>>(row, col, w, dinv, t_a, t_b);
    k_greduce<<<100, C, 0, stream>>>(dinv, t_a, t_b, s1, b1, g);
    k_final  <<<1, C, 0, stream>>>(g, W2, b2, out);
}